// Round 6
// baseline (133.410 us; speedup 1.0000x reference)
//
#include <hip/hip_runtime.h>

// MultiheadAttention fused, v4.
// 3 kernels: repack(W), proj (fp32 x direct, fused bias + V-transpose epilogue),
// attn (triple-buffered gload_lds staging, counted vmcnt, one barrier/iter).
// B=2 H=8 S=2048 E=64 F=512. f16 MFMA internally.

using half8  = __attribute__((ext_vector_type(8))) _Float16;
using f32x4  = __attribute__((ext_vector_type(4))) float;
using float4v = __attribute__((ext_vector_type(4))) float;
using uint2v = __attribute__((ext_vector_type(2))) unsigned int;
using uint4v = __attribute__((ext_vector_type(4))) unsigned int;

constexpr int BN = 2, HN = 8, SN = 2048, EN = 64, FN = 512;
constexpr size_t T_ELEMS = (size_t)BN * HN * SN * EN;      // 2M per tensor

constexpr size_t WB_BYTES = (size_t)24 * 16 * 4 * 64 * 8 * 2;   // 1.5 MB
constexpr size_t BP_OFF   = WB_BYTES;
constexpr size_t VT_OFF   = BP_OFF + 1536 * 4;
constexpr size_t VT_BYTES = T_ELEMS * 2;                        // 4 MB
constexpr size_t QKV_OFF  = VT_OFF + VT_BYTES;

__device__ inline unsigned int pack2h(float a, float b) {
  auto h = __builtin_amdgcn_cvt_pkrtz(a, b);
  return __builtin_bit_cast(unsigned int, h);
}

__device__ __forceinline__ void async_copy16(void* lds, const void* g) {
  __builtin_amdgcn_global_load_lds(
      (const __attribute__((address_space(1))) unsigned int*)g,
      (__attribute__((address_space(3))) unsigned int*)lds, 16, 0, 0);
}

// ---------------- kernel 1: W repack (coalesced frag-layout writes)
__global__ __launch_bounds__(256) void repack_kernel(
    const float* __restrict__ W, const float* __restrict__ bias,
    _Float16* __restrict__ Wb, float* __restrict__ bp) {
  int t = blockIdx.x * 256 + threadIdx.x;
  int lane = t & 63;
  int cb = (t >> 6) & 3;
  int kc = (t >> 8) & 15;
  int ch = t >> 12;
  int e = cb * 16 + (lane & 15);
  int fb = kc * 32 + (lane >> 4) * 8;
  int c = ch >> 3, h = ch & 7;
  int j = e * 24 + h * 3 + c;
  half8 o;
  #pragma unroll
  for (int i = 0; i < 8; ++i) o[i] = (_Float16)W[(size_t)(fb + i) * 1536 + j];
  *(half8*)(Wb + (size_t)t * 8) = o;
  if (t < 1536) {
    int cc = t % 3, hh = (t / 3) & 7, ee = t / 24;
    bp[(cc * 8 + hh) * 64 + ee] = bias[t];
  }
}

// ---------------- kernel 2: projection GEMM [4096x512]@[512x1536], grid (64,8).
// Reads fp32 x directly; for V channels (c==2) transposes through LDS and
// writes V^T [bh][e][s] directly (vtrans fused).
__global__ __launch_bounds__(256) void proj_kernel(
    const float* __restrict__ x, const _Float16* __restrict__ Wb,
    const float* __restrict__ bp, _Float16* __restrict__ qkv,
    _Float16* __restrict__ vt) {
  __shared__ _Float16 tl[64 * 72];
  int rt = blockIdx.x, cg = blockIdx.y;
  int wave = threadIdx.x >> 6, lane = threadIdx.x & 63;
  int lcol = lane & 15, lg = lane >> 4;
  int row0 = rt * 64 + wave * 16;
  f32x4 acc[3][4] = {};
  const float* xr = x + (size_t)(row0 + lcol) * FN;
  for (int kc = 0; kc < 16; ++kc) {
    const float4v* xp = (const float4v*)(xr + kc * 32 + lg * 8);
    float4v x0 = xp[0], x1 = xp[1];
    half8 a;
    #pragma unroll
    for (int i = 0; i < 4; ++i) { a[i] = (_Float16)x0[i]; a[4 + i] = (_Float16)x1[i]; }
    #pragma unroll
    for (int chi = 0; chi < 3; ++chi) {
      int ch = cg * 3 + chi;
      #pragma unroll
      for (int cb = 0; cb < 4; ++cb) {
        half8 bfr = *(const half8*)(Wb + ((((size_t)ch * 16 + kc) * 4 + cb) * 64 + lane) * 8);
        acc[chi][cb] = __builtin_amdgcn_mfma_f32_16x16x32_f16(a, bfr, acc[chi][cb], 0, 0, 0);
      }
    }
  }
  int b = rt >> 5, s0 = (rt & 31) * 64;
  #pragma unroll
  for (int chi = 0; chi < 3; ++chi) {
    int ch = cg * 3 + chi;
    int c = ch >> 3, h = ch & 7;
    if (c < 2) {
      _Float16* dst = qkv + (size_t)c * T_ELEMS;
      #pragma unroll
      for (int cb = 0; cb < 4; ++cb) {
        int e = cb * 16 + lcol;
        float bv = bp[ch * 64 + e];
        #pragma unroll
        for (int r = 0; r < 4; ++r) {
          int s = s0 + wave * 16 + lg * 4 + r;
          dst[((size_t)(b * HN + h) * SN + s) * EN + e] = (_Float16)(acc[chi][cb][r] + bv);
        }
      }
    } else {
      // V channel: stage 64x64 tile (s_local x e) in LDS, write transposed rows
      #pragma unroll
      for (int cb = 0; cb < 4; ++cb) {
        int e = cb * 16 + lcol;
        float bv = bp[ch * 64 + e];
        #pragma unroll
        for (int r = 0; r < 4; ++r)
          tl[(wave * 16 + lg * 4 + r) * 72 + e] = (_Float16)(acc[chi][cb][r] + bv);
      }
      __syncthreads();
      int e = threadIdx.x >> 2, sc = threadIdx.x & 3;
      half8 o0, o1;
      #pragma unroll
      for (int i = 0; i < 8; ++i) o0[i] = tl[(sc * 16 + i) * 72 + e];
      #pragma unroll
      for (int i = 0; i < 8; ++i) o1[i] = tl[(sc * 16 + 8 + i) * 72 + e];
      _Float16* dstv = vt + ((size_t)(b * HN + h) * EN + e) * SN + s0 + sc * 16;
      *(half8*)dstv = o0;
      *(half8*)(dstv + 8) = o1;
      __syncthreads();
    }
  }
}

// ---------------- kernel 3: flash attention v4.
// grid 512 = 16 bh x 32 q-blocks (64 rows). 4 waves x 16 q-rows.
// K/V^T tiles (64 keys) triple-buffered in LDS via global_load_lds w16,
// XOR-swizzled (byte ^= (row&7)<<4) with pre-swizzled global source.
// Counted vmcnt(4): loads stay in flight across the single per-iter barrier.
__global__ __launch_bounds__(256, 2) void attn_kernel(
    const _Float16* __restrict__ q_ws, const _Float16* __restrict__ k_ws,
    const _Float16* __restrict__ vt_ws, float* __restrict__ out) {
  // [0,49152): 3 KV buffers (16 KB each: K @+0, V @+8192)
  // [49152,57344): per-wave P transpose (2 KB each)
  // epilogue: per-wave O transpose 4 KB at wave*4096 (aliases buf0, post-loop)
  __shared__ __align__(16) char smem[57344];

  int bid = blockIdx.x;
  int lb = (bid & 7) * 64 + (bid >> 3);          // XCD swizzle (512 % 8 == 0)
  int bh = lb >> 5, qblk = lb & 31;
  int wave = threadIdx.x >> 6, lane = threadIdx.x & 63;
  int q = lane & 15, g = lane >> 4;
  int q0 = qblk * 64 + wave * 16;

  const _Float16* qb  = q_ws  + ((size_t)bh * SN + q0) * EN;
  const _Float16* kb  = k_ws  + (size_t)bh * SN * EN;
  const _Float16* vtb = vt_ws + (size_t)bh * EN * SN;

  half8 qf[2];
  qf[0] = *(const half8*)(qb + (size_t)q * EN + g * 8);
  qf[1] = *(const half8*)(qb + (size_t)q * EN + 32 + g * 8);

  f32x4 o[4] = {};                  // O^T: col=q, row e = et*16 + g*4 + r
  float m = -3e38f, l = 0.f;
  unsigned int* pw = (unsigned int*)(smem + 49152 + wave * 2048);

  int sub = lane >> 3;
  int off8 = ((lane & 7) ^ sub) * 8;
  int lin = lane * 16;

  auto stage = [&](int c, int t) {   // 4 gload_lds per lane
    char* kbuf = smem + c * 16384;
    char* vbuf = kbuf + 8192;
    int kv = t * 64;
    #pragma unroll
    for (int ii = 0; ii < 2; ++ii) {
      int i = wave * 2 + ii;
      int row = i * 8 + sub;
      async_copy16(kbuf + i * 1024 + lin, kb + (size_t)(kv + row) * EN + off8);
      async_copy16(vbuf + i * 1024 + lin, vtb + (size_t)row * SN + kv + off8);
    }
  };

  int qx = (q & 7) << 4;

  auto compute = [&](int c) {
    const char* kbuf = smem + c * 16384;
    const char* vbuf = kbuf + 8192;
    half8 kf[4][2], vf[4][2];
    #pragma unroll
    for (int kt = 0; kt < 4; ++kt)
      #pragma unroll
      for (int eh = 0; eh < 2; ++eh)
        kf[kt][eh] = *(const half8*)(kbuf + ((((kt * 16 + q) * 128) + eh * 64 + g * 16) ^ qx));
    #pragma unroll
    for (int et = 0; et < 4; ++et)
      #pragma unroll
      for (int kh = 0; kh < 2; ++kh)
        vf[et][kh] = *(const half8*)(vbuf + ((((et * 16 + q) * 128) + kh * 64 + g * 16) ^ qx));

    f32x4 s[4];
    f32x4 z = {};
    __builtin_amdgcn_s_setprio(1);
    #pragma unroll
    for (int kt = 0; kt < 4; ++kt) {
      s[kt] = __builtin_amdgcn_mfma_f32_16x16x32_f16(kf[kt][0], qf[0], z, 0, 0, 0);
      s[kt] = __builtin_amdgcn_mfma_f32_16x16x32_f16(kf[kt][1], qf[1], s[kt], 0, 0, 0);
    }
    __builtin_amdgcn_s_setprio(0);

    float mx = s[0][0];
    #pragma unroll
    for (int kt = 0; kt < 4; ++kt)
      #pragma unroll
      for (int r = 0; r < 4; ++r) mx = fmaxf(mx, s[kt][r]);
    mx = fmaxf(mx, __shfl_xor(mx, 16));
    mx = fmaxf(mx, __shfl_xor(mx, 32));
    if (!__all(mx <= m + 8.f)) {     // defer-max, THR=8
      float mn = fmaxf(m, mx);
      float scl = __expf(m - mn);
      m = mn;
      l *= scl;
      #pragma unroll
      for (int et = 0; et < 4; ++et)
        #pragma unroll
        for (int r = 0; r < 4; ++r) o[et][r] *= scl;
    }
    float ps = 0.f;
    #pragma unroll
    for (int kt = 0; kt < 4; ++kt) {
      float p0 = __expf(s[kt][0] - m), p1 = __expf(s[kt][1] - m);
      float p2 = __expf(s[kt][2] - m), p3 = __expf(s[kt][3] - m);
      ps += (p0 + p1) + (p2 + p3);
      uint2v wv;
      wv.x = pack2h(p0, p1);
      wv.y = pack2h(p2, p3);
      int w = kt * 8 + 2 * g;                  // chunk-rotated P^T transpose
      int phys = (((w >> 2) + q) & 7) * 4 + (w & 3);
      *(uint2v*)&pw[q * 32 + phys] = wv;
    }
    l += ps;
    asm volatile("s_waitcnt lgkmcnt(0)" ::: "memory");
    __builtin_amdgcn_sched_barrier(0);
    half8 pf[2];
    #pragma unroll
    for (int kh = 0; kh < 2; ++kh) {
      int cc = kh * 4 + g;
      uint4v tv = *(const uint4v*)&pw[q * 32 + ((cc + q) & 7) * 4];
      pf[kh] = __builtin_bit_cast(half8, tv);
    }
    __builtin_amdgcn_sched_barrier(0);
    __builtin_amdgcn_s_setprio(1);
    #pragma unroll
    for (int et = 0; et < 4; ++et) {
      o[et] = __builtin_amdgcn_mfma_f32_16x16x32_f16(vf[et][0], pf[0], o[et], 0, 0, 0);
      o[et] = __builtin_amdgcn_mfma_f32_16x16x32_f16(vf[et][1], pf[1], o[et], 0, 0, 0);
    }
    __builtin_amdgcn_s_setprio(0);
  };

  stage(0, 0);
  stage(1, 1);
  for (int t = 0; t < 31; ++t) {
    asm volatile("s_waitcnt vmcnt(4)" ::: "memory");   // own tile-t loads landed
    __syncthreads();                                    // => everyone's tile-t landed
    if (t + 2 < 32) stage((t + 2) % 3, t + 2);          // keep 4-8 loads in flight
    compute(t % 3);
  }
  asm volatile("s_waitcnt vmcnt(0)" ::: "memory");      // peeled last iter
  __syncthreads();
  compute(31 % 3);

  // epilogue: O^T -> per-wave LDS transpose (aliases buf0/buf1) -> coalesced stores
  l += __shfl_xor(l, 16);
  l += __shfl_xor(l, 32);
  float rl = 1.f / l;
  int b = bh >> 3, h = bh & 7;
  float* ow = (float*)(smem + wave * 4096);
  #pragma unroll
  for (int et = 0; et < 4; ++et)
    #pragma unroll
    for (int r = 0; r < 4; ++r) {
      int e = et * 16 + g * 4 + r;
      ow[q * 64 + ((e + q * 4) & 63)] = o[et][r] * rl;
    }
  asm volatile("s_waitcnt lgkmcnt(0)" ::: "memory");
  __builtin_amdgcn_sched_barrier(0);
  #pragma unroll
  for (int qr = 0; qr < 16; ++qr) {
    float vvv = ow[qr * 64 + ((lane + qr * 4) & 63)];
    out[((size_t)b * SN + q0 + qr) * 512 + h * 64 + lane] = vvv;
  }
}

extern "C" void kernel_launch(void* const* d_in, const int* in_sizes, int n_in,
                              void* d_out, int out_size, void* d_ws, size_t ws_size,
                              hipStream_t stream) {
  const float* x    = (const float*)d_in[0];
  const float* W    = (const float*)d_in[1];
  const float* bias = (const float*)d_in[2];
  float* out = (float*)d_out;
  char* ws = (char*)d_ws;
  _Float16* Wb  = (_Float16*)(ws);
  float*    bp  = (float*)(ws + BP_OFF);
  _Float16* vt  = (_Float16*)(ws + VT_OFF);
  _Float16* qkv = (_Float16*)(ws + QKV_OFF);

  repack_kernel<<<384, 256, 0, stream>>>(W, bias, Wb, bp);
  proj_kernel<<<dim3(64, 8), 256, 0, stream>>>(x, Wb, bp, qkv, vt);
  attn_kernel<<<512, 256, 0, stream>>>(qkv, qkv + T_ELEMS, vt, out);
}

// Round 7
// 120.115 us; speedup vs baseline: 1.1107x; 1.1107x over previous
//
#include <hip/hip_runtime.h>

// MultiheadAttention fused, v5.
// prep: x->f16 + W deinterleave->Wd[n][f] f16 + bias deinterleave (one kernel).
// proj: 128x128xBK64 LDS-staged GEMM (gload_lds w16, XOR swizzle, counted vmcnt),
//       epilogue writes Q,K rows and V^T directly.
// attn: UNCHANGED from v4 (triple-buffered staging, counted vmcnt).
// B=2 H=8 S=2048 E=64 F=512. f16 MFMA internally.

using half4v = __attribute__((ext_vector_type(4))) _Float16;
using half8  = __attribute__((ext_vector_type(8))) _Float16;
using f32x4  = __attribute__((ext_vector_type(4))) float;
using float4v = __attribute__((ext_vector_type(4))) float;
using uint2v = __attribute__((ext_vector_type(2))) unsigned int;
using uint4v = __attribute__((ext_vector_type(4))) unsigned int;

constexpr int BN = 2, HN = 8, SN = 2048, EN = 64, FN = 512;
constexpr size_t T_ELEMS = (size_t)BN * HN * SN * EN;      // 2M per tensor

// ws: Wd [1536][512] f16 | bpn [1536] f32 | x16 [4096][512] f16 | vt 4MB | Q,K 8MB
constexpr size_t WD_BYTES = (size_t)1536 * 512 * 2;             // 1.5 MB
constexpr size_t BPN_OFF  = WD_BYTES;
constexpr size_t X16_OFF  = BPN_OFF + 1536 * 4;
constexpr size_t X16_BYTES = (size_t)4096 * 512 * 2;            // 4 MB
constexpr size_t VT_OFF   = X16_OFF + X16_BYTES;
constexpr size_t VT_BYTES = T_ELEMS * 2;                        // 4 MB
constexpr size_t QKV_OFF  = VT_OFF + VT_BYTES;

__device__ inline unsigned int pack2h(float a, float b) {
  auto h = __builtin_amdgcn_cvt_pkrtz(a, b);
  return __builtin_bit_cast(unsigned int, h);
}

__device__ __forceinline__ void async_copy16(void* lds, const void* g) {
  __builtin_amdgcn_global_load_lds(
      (const __attribute__((address_space(1))) unsigned int*)g,
      (__attribute__((address_space(3))) unsigned int*)lds, 16, 0, 0);
}

// ---------------- kernel 1: prep. x->f16 (all threads), W gather-deinterleave
// Wd[n][f] (n = ch*64+e, ch = c*8+h; orig col j = e*24+h*3+c), bias deint.
__global__ __launch_bounds__(256) void prep_kernel(
    const float* __restrict__ x, const float* __restrict__ W,
    const float* __restrict__ bias, _Float16* __restrict__ x16,
    _Float16* __restrict__ Wd, float* __restrict__ bpn) {
  int t = blockIdx.x * 256 + threadIdx.x;          // 262144 threads
  const float4v* src = (const float4v*)(x + (size_t)t * 8);
  float4v a = src[0], b = src[1];
  half8 o;
  #pragma unroll
  for (int i = 0; i < 4; ++i) { o[i] = (_Float16)a[i]; o[4 + i] = (_Float16)b[i]; }
  *(half8*)(x16 + (size_t)t * 8) = o;

  if (t < 1536 * 64) {                             // Wd gather: wave = one n-row
    int n = t >> 6, cc = t & 63, fb = cc * 8;
    int ch = n >> 6, e = n & 63, c = ch >> 3, h = ch & 7;
    int j = e * 24 + h * 3 + c;
    half8 w;
    #pragma unroll
    for (int i = 0; i < 8; ++i) w[i] = (_Float16)W[(size_t)(fb + i) * 1536 + j];
    *(half8*)(Wd + (size_t)n * 512 + fb) = w;
  }
  if (t < 1536) {
    int ch = t >> 6, e = t & 63, c = ch >> 3, h = ch & 7;
    bpn[t] = bias[e * 24 + h * 3 + c];
  }
}

// ---------------- kernel 2: proj GEMM. C[4096][1536] = x16 @ Wd^T + bpn.
// BM=128 BN=128 BK=64, grid (32,12), 4 waves (wave-tile 64x64).
// A_lds[m][64k], B_lds[n][64k], XOR-swizzled (byte ^= (row&7)<<4) via
// pre-swizzled global source + linear gload_lds dest. Double buffer, vmcnt(8).
// Epilogue: cols 0-511 Q rows, 512-1023 K rows, 1024-1535 -> V^T (8B col stores).
__global__ __launch_bounds__(256, 2) void proj_kernel(
    const _Float16* __restrict__ x16, const _Float16* __restrict__ Wd,
    const float* __restrict__ bpn, _Float16* __restrict__ qkv,
    _Float16* __restrict__ vt) {
  __shared__ __align__(16) char smem[65536];   // A0,A1,B0,B1 @ 0,16K,32K,48K

  int tid = threadIdx.x;
  int wave = tid >> 6, lane = tid & 63;
  int q16 = lane & 15, g = lane >> 4;
  int wm = wave >> 1, wn = wave & 1;
  int gm_blk = blockIdx.x * 128, gn_blk = blockIdx.y * 128;

  f32x4 acc[4][4] = {};   // [mt][nt]; row m = wm*64+mt*16+g*4+r, col n = wn*64+nt*16+q16

  auto stage = [&](int c, int ks) {
    char* Ab = smem + c * 16384;
    char* Bb = smem + 32768 + c * 16384;
    int k0 = ks * 64;
    #pragma unroll
    for (int ii = 0; ii < 4; ++ii) {
      int qq = tid + 256 * ii;
      int row = qq >> 3, cc = qq & 7;
      int sc = (cc ^ (row & 7)) * 8;
      async_copy16(Ab + qq * 16, x16 + (size_t)(gm_blk + row) * 512 + k0 + sc);
      async_copy16(Bb + qq * 16, Wd + (size_t)(gn_blk + row) * 512 + k0 + sc);
    }
  };

  auto compute = [&](int c) {
    const char* Ab = smem + c * 16384;
    const char* Bb = smem + 32768 + c * 16384;
    #pragma unroll
    for (int kh = 0; kh < 2; ++kh) {
      half8 af[4], bf[4];
      #pragma unroll
      for (int mt = 0; mt < 4; ++mt) {
        int m = wm * 64 + mt * 16 + q16;
        af[mt] = *(const half8*)(Ab + m * 128 + ((kh * 64 + g * 16) ^ ((m & 7) << 4)));
      }
      #pragma unroll
      for (int nt = 0; nt < 4; ++nt) {
        int n = wn * 64 + nt * 16 + q16;
        bf[nt] = *(const half8*)(Bb + n * 128 + ((kh * 64 + g * 16) ^ ((n & 7) << 4)));
      }
      __builtin_amdgcn_s_setprio(1);
      #pragma unroll
      for (int mt = 0; mt < 4; ++mt)
        #pragma unroll
        for (int nt = 0; nt < 4; ++nt)
          acc[mt][nt] = __builtin_amdgcn_mfma_f32_16x16x32_f16(af[mt], bf[nt], acc[mt][nt], 0, 0, 0);
      __builtin_amdgcn_s_setprio(0);
    }
  };

  stage(0, 0);
  #pragma unroll
  for (int ks = 0; ks < 8; ++ks) {
    int cur = ks & 1;
    __syncthreads();                       // everyone done reading buf cur^1
    if (ks + 1 < 8) {
      stage(cur ^ 1, ks + 1);
      asm volatile("s_waitcnt vmcnt(8)" ::: "memory");   // tile-ks loads landed
    } else {
      asm volatile("s_waitcnt vmcnt(0)" ::: "memory");
    }
    __syncthreads();
    compute(cur);
  }

  // epilogue: one ch (64 cols) per wave-column
  int gn0 = gn_blk + wn * 64;
  int ch = gn0 >> 6, c = ch >> 3, h = ch & 7;
  int gm0 = gm_blk + wm * 64;
  if (c < 2) {
    _Float16* dst = qkv + (size_t)c * T_ELEMS;
    #pragma unroll
    for (int nt = 0; nt < 4; ++nt) {
      int e = nt * 16 + q16;
      float bv = bpn[gn0 + nt * 16 + q16];
      #pragma unroll
      for (int mt = 0; mt < 4; ++mt)
        #pragma unroll
        for (int r = 0; r < 4; ++r) {
          int gm = gm0 + mt * 16 + g * 4 + r;
          int b = gm >> 11, s = gm & 2047;
          dst[((size_t)(b * HN + h) * SN + s) * EN + e] = (_Float16)(acc[mt][nt][r] + bv);
        }
    }
  } else {
    #pragma unroll
    for (int nt = 0; nt < 4; ++nt) {
      int e = nt * 16 + q16;
      float bv = bpn[gn0 + nt * 16 + q16];
      #pragma unroll
      for (int mt = 0; mt < 4; ++mt) {
        int gm = gm0 + mt * 16 + g * 4;
        int b = gm >> 11, s = gm & 2047;
        half4v hv;
        #pragma unroll
        for (int r = 0; r < 4; ++r) hv[r] = (_Float16)(acc[mt][nt][r] + bv);
        *(half4v*)(vt + ((size_t)(b * HN + h) * EN + e) * SN + s) = hv;
      }
    }
  }
}

// ---------------- kernel 3: flash attention (v4, unchanged).
__global__ __launch_bounds__(256, 2) void attn_kernel(
    const _Float16* __restrict__ q_ws, const _Float16* __restrict__ k_ws,
    const _Float16* __restrict__ vt_ws, float* __restrict__ out) {
  __shared__ __align__(16) char smem[57344];

  int bid = blockIdx.x;
  int lb = (bid & 7) * 64 + (bid >> 3);          // XCD swizzle (512 % 8 == 0)
  int bh = lb >> 5, qblk = lb & 31;
  int wave = threadIdx.x >> 6, lane = threadIdx.x & 63;
  int q = lane & 15, g = lane >> 4;
  int q0 = qblk * 64 + wave * 16;

  const _Float16* qb  = q_ws  + ((size_t)bh * SN + q0) * EN;
  const _Float16* kb  = k_ws  + (size_t)bh * SN * EN;
  const _Float16* vtb = vt_ws + (size_t)bh * EN * SN;

  half8 qf[2];
  qf[0] = *(const half8*)(qb + (size_t)q * EN + g * 8);
  qf[1] = *(const half8*)(qb + (size_t)q * EN + 32 + g * 8);

  f32x4 o[4] = {};                  // O^T: col=q, row e = et*16 + g*4 + r
  float m = -3e38f, l = 0.f;
  unsigned int* pw = (unsigned int*)(smem + 49152 + wave * 2048);

  int sub = lane >> 3;
  int off8 = ((lane & 7) ^ sub) * 8;
  int lin = lane * 16;

  auto stage = [&](int c, int t) {   // 4 gload_lds per lane
    char* kbuf = smem + c * 16384;
    char* vbuf = kbuf + 8192;
    int kv = t * 64;
    #pragma unroll
    for (int ii = 0; ii < 2; ++ii) {
      int i = wave * 2 + ii;
      int row = i * 8 + sub;
      async_copy16(kbuf + i * 1024 + lin, kb + (size_t)(kv + row) * EN + off8);
      async_copy16(vbuf + i * 1024 + lin, vtb + (size_t)row * SN + kv + off8);
    }
  };

  int qx = (q & 7) << 4;

  auto compute = [&](int c) {
    const char* kbuf = smem + c * 16384;
    const char* vbuf = kbuf + 8192;
    half8 kf[4][2], vf[4][2];
    #pragma unroll
    for (int kt = 0; kt < 4; ++kt)
      #pragma unroll
      for (int eh = 0; eh < 2; ++eh)
        kf[kt][eh] = *(const half8*)(kbuf + ((((kt * 16 + q) * 128) + eh * 64 + g * 16) ^ qx));
    #pragma unroll
    for (int et = 0; et < 4; ++et)
      #pragma unroll
      for (int kh = 0; kh < 2; ++kh)
        vf[et][kh] = *(const half8*)(vbuf + ((((et * 16 + q) * 128) + kh * 64 + g * 16) ^ qx));

    f32x4 s[4];
    f32x4 z = {};
    __builtin_amdgcn_s_setprio(1);
    #pragma unroll
    for (int kt = 0; kt < 4; ++kt) {
      s[kt] = __builtin_amdgcn_mfma_f32_16x16x32_f16(kf[kt][0], qf[0], z, 0, 0, 0);
      s[kt] = __builtin_amdgcn_mfma_f32_16x16x32_f16(kf[kt][1], qf[1], s[kt], 0, 0, 0);
    }
    __builtin_amdgcn_s_setprio(0);

    float mx = s[0][0];
    #pragma unroll
    for (int kt = 0; kt < 4; ++kt)
      #pragma unroll
      for (int r = 0; r < 4; ++r) mx = fmaxf(mx, s[kt][r]);
    mx = fmaxf(mx, __shfl_xor(mx, 16));
    mx = fmaxf(mx, __shfl_xor(mx, 32));
    if (!__all(mx <= m + 8.f)) {     // defer-max, THR=8
      float mn = fmaxf(m, mx);
      float scl = __expf(m - mn);
      m = mn;
      l *= scl;
      #pragma unroll
      for (int et = 0; et < 4; ++et)
        #pragma unroll
        for (int r = 0; r < 4; ++r) o[et][r] *= scl;
    }
    float ps = 0.f;
    #pragma unroll
    for (int kt = 0; kt < 4; ++kt) {
      float p0 = __expf(s[kt][0] - m), p1 = __expf(s[kt][1] - m);
      float p2 = __expf(s[kt][2] - m), p3 = __expf(s[kt][3] - m);
      ps += (p0 + p1) + (p2 + p3);
      uint2v wv;
      wv.x = pack2h(p0, p1);
      wv.y = pack2h(p2, p3);
      int w = kt * 8 + 2 * g;                  // chunk-rotated P^T transpose
      int phys = (((w >> 2) + q) & 7) * 4 + (w & 3);
      *(uint2v*)&pw[q * 32 + phys] = wv;
    }
    l += ps;
    asm volatile("s_waitcnt lgkmcnt(0)" ::: "memory");
    __builtin_amdgcn_sched_barrier(0);
    half8 pf[2];
    #pragma unroll
    for (int kh = 0; kh < 2; ++kh) {
      int cc = kh * 4 + g;
      uint4v tv = *(const uint4v*)&pw[q * 32 + ((cc + q) & 7) * 4];
      pf[kh] = __builtin_bit_cast(half8, tv);
    }
    __builtin_amdgcn_sched_barrier(0);
    __builtin_amdgcn_s_setprio(1);
    #pragma unroll
    for (int et = 0; et < 4; ++et) {
      o[et] = __builtin_amdgcn_mfma_f32_16x16x32_f16(vf[et][0], pf[0], o[et], 0, 0, 0);
      o[et] = __builtin_amdgcn_mfma_f32_16x16x32_f16(vf[et][1], pf[1], o[et], 0, 0, 0);
    }
    __builtin_amdgcn_s_setprio(0);
  };

  stage(0, 0);
  stage(1, 1);
  for (int t = 0; t < 31; ++t) {
    asm volatile("s_waitcnt vmcnt(4)" ::: "memory");   // own tile-t loads landed
    __syncthreads();                                    // => everyone's tile-t landed
    if (t + 2 < 32) stage((t + 2) % 3, t + 2);          // keep 4-8 loads in flight
    compute(t % 3);
  }
  asm volatile("s_waitcnt vmcnt(0)" ::: "memory");      // peeled last iter
  __syncthreads();
  compute(31 % 3);

  // epilogue: O^T -> per-wave LDS transpose (aliases buf0/buf1) -> coalesced stores
  l += __shfl_xor(l, 16);
  l += __shfl_xor(l, 32);
  float rl = 1.f / l;
  int b = bh >> 3, h = bh & 7;
  float* ow = (float*)(smem + wave * 4096);
  #pragma unroll
  for (int et = 0; et < 4; ++et)
    #pragma unroll
    for (int r = 0; r < 4; ++r) {
      int e = et * 16 + g * 4 + r;
      ow[q * 64 + ((e + q * 4) & 63)] = o[et][r] * rl;
    }
  asm volatile("s_waitcnt lgkmcnt(0)" ::: "memory");
  __builtin_amdgcn_sched_barrier(0);
  #pragma unroll
  for (int qr = 0; qr < 16; ++qr) {
    float vvv = ow[qr * 64 + ((lane + qr * 4) & 63)];
    out[((size_t)b * SN + q0 + qr) * 512 + h * 64 + lane] = vvv;
  }
}

extern "C" void kernel_launch(void* const* d_in, const int* in_sizes, int n_in,
                              void* d_out, int out_size, void* d_ws, size_t ws_size,
                              hipStream_t stream) {
  const float* x    = (const float*)d_in[0];
  const float* W    = (const float*)d_in[1];
  const float* bias = (const float*)d_in[2];
  float* out = (float*)d_out;
  char* ws = (char*)d_ws;
  _Float16* Wd  = (_Float16*)(ws);
  float*    bpn = (float*)(ws + BPN_OFF);
  _Float16* x16 = (_Float16*)(ws + X16_OFF);
  _Float16* vt  = (_Float16*)(ws + VT_OFF);
  _Float16* qkv = (_Float16*)(ws + QKV_OFF);   // Q @0, K @T_ELEMS

  prep_kernel<<<1024, 256, 0, stream>>>(x, W, bias, x16, Wd, bpn);
  proj_kernel<<<dim3(32, 12), 256, 0, stream>>>(x16, Wd, bpn, qkv, vt);
  attn_kernel<<<512, 256, 0, stream>>>(qkv, qkv + T_ELEMS, vt, out);
}